// Round 21
// baseline (220.268 us; speedup 1.0000x reference)
//
#include <hip/hip_runtime.h>
#include <hip/hip_cooperative_groups.h>

namespace cg = cooperative_groups;

// AttentiveConv3d: B=2, C=128, T=16, H=W=28, heads=2, HS=64, K=27 (3x3x3, pad 1)
// Round 21: single cooperative kernel (part1 = s-field + W->bf16, grid.sync,
// part2 = fusedmp A/B/C) to remove the second dispatch + gap. Falls back to
// the proven r20 two-kernel path if cooperative launch is unavailable.

#define TT 16
#define HH 28
#define WW 28
#define CC 128
#define SP (TT * HH * WW)   // 12544 = 448*28, 98*128
#define NPOS (2 * SP)       // 25088 = 196*128
#define HS 64
#define KT 27
#define MTS 136             // padded bf16 stride for s_mt

typedef __attribute__((ext_vector_type(8))) short bf16x8;
typedef __attribute__((ext_vector_type(4))) float f32x4;

#define CLMP(a) ((a) < 0 ? 0 : ((a) > 15 ? 15 : (a)))

__device__ __forceinline__ unsigned short bf16_rtne(float f) {
    unsigned u = __float_as_uint(f);
    unsigned r = (u + 0x7FFFu + ((u >> 16) & 1u)) >> 16;
    return (unsigned short)r;
}

// ---------- shared device bodies ----------

// s-field over 128 consecutive positions (f4 per lane). cb = chunk index 0..195
__device__ __forceinline__ void qfield_body(
    const float* __restrict__ x, const float* __restrict__ q,
    float* __restrict__ s, int cb, int tid, float4 (*sp)[32])
{
    const int pl  = tid & 31;         // f4 slot within chunk
    const int g   = tid >> 5;         // channel group 0..7
    const int p   = cb * 128 + pl * 4;
    const int b   = p / SP;
    const int si  = p % SP;
    const float* xb = x + (size_t)b * CC * SP + si;

    float4 a0 = make_float4(0.f, 0.f, 0.f, 0.f);
    float4 a1 = make_float4(0.f, 0.f, 0.f, 0.f);
    #pragma unroll
    for (int j = 0; j < 16; ++j) {
        const int c = g * 16 + j;
        const float4 val = *(const float4*)&xb[(size_t)c * SP];
        const float qv   = q[(c & 1) * HS + (c >> 1)] * (1.0f / 64.0f);
        if (c & 1) {
            a1.x += qv * val.x; a1.y += qv * val.y;
            a1.z += qv * val.z; a1.w += qv * val.w;
        } else {
            a0.x += qv * val.x; a0.y += qv * val.y;
            a0.z += qv * val.z; a0.w += qv * val.w;
        }
    }
    sp[g][pl]     = a0;
    sp[8 + g][pl] = a1;
    __syncthreads();
    if (tid < 64) {
        const int h = tid >> 5, pp = tid & 31;
        float4 a = make_float4(0.f, 0.f, 0.f, 0.f);
        #pragma unroll
        for (int g2 = 0; g2 < 8; ++g2) {
            const float4 v = sp[h * 8 + g2][pp];
            a.x += v.x; a.y += v.y; a.z += v.z; a.w += v.w;
        }
        *(float4*)&s[h * NPOS + cb * 128 + pp * 4] = a;
    }
}

// phase B worker: HALF is compile-time -> all xr/acc indices constant-fold.
template<int HALF>
__device__ __forceinline__ void phaseB_row(
    const float* __restrict__ xc, const float (*s_aw)[2][32], int h,
    int t, int u0, unsigned short (*s_mt)[MTS], int c)
{
    float acc[16];
    #pragma unroll
    for (int i = 0; i < 16; ++i) acc[i] = 0.f;

    #pragma unroll
    for (int dt = -1; dt <= 1; ++dt) {
        #pragma unroll
        for (int du = -1; du <= 1; ++du) {
            const int tt = t + dt, uu = u0 + du;
            const bool rok = ((unsigned)tt < TT) && ((unsigned)uu < HH);
            const int rbase = rok ? (tt * HH + uu) * WW : 0;  // aw=0 if row OOB
            float xr[16];                       // vv = HALF*12 .. HALF*12+15
            #pragma unroll
            for (int j = 0; j < 4; ++j) {
                const float4 tmp = *(const float4*)&xc[rbase + HALF * 12 + 4 * j];
                xr[4*j+0] = tmp.x; xr[4*j+1] = tmp.y;
                xr[4*j+2] = tmp.z; xr[4*j+3] = tmp.w;
            }
            const int kb = ((dt + 1) * 3 + (du + 1)) * 3;     // k = kb + dv
            #pragma unroll
            for (int dv = 0; dv < 3; ++dv) {
                const float4* aw4 = (const float4*)&s_aw[kb + dv][h][HALF * 16];
                #pragma unroll
                for (int j = 0; j < 4; ++j) {
                    const float4 a4 = aw4[j];
                    const int ib = 4 * j;
                    acc[ib+0] += a4.x * xr[CLMP(ib+0 + dv - 1 + 2*HALF)];
                    acc[ib+1] += a4.y * xr[CLMP(ib+1 + dv - 1 + 2*HALF)];
                    acc[ib+2] += a4.z * xr[CLMP(ib+2 + dv - 1 + 2*HALF)];
                    acc[ib+3] += a4.w * xr[CLMP(ib+3 + dv - 1 + 2*HALF)];
                }
            }
        }
    }
    #pragma unroll
    for (int i = 0; i < 14; ++i)                 // i=14,15 are dummies
        s_mt[HALF * 14 + i][c] = bf16_rtne(acc[i]);
}

// fusedmp body for one 28-p tile (pb already swizzle-decoded)
__device__ __forceinline__ void fusedmp_body(
    const float* __restrict__ x, const float* __restrict__ s,
    const unsigned short* __restrict__ Wb, const float* __restrict__ bout,
    float* __restrict__ out, int pb, int tid,
    float (*s_aw)[2][32], unsigned short (*s_mt)[MTS])
{
    const int b    = pb / 448;                 // 448 rows per batch
    const int tile = pb % 448;
    const int p0   = tile * 28;
    const int t    = tile / 28;                // 0..15
    const int u0   = tile % 28;                // 0..27

    // zero pad rows 28..31 of s_mt (phase C reads them in the tail p-tile)
    {
        unsigned* z = (unsigned*)&s_mt[28][0];    // 4*MTS u16 = 2*MTS words
        for (int i = tid; i < 2 * MTS; i += 256) z[i] = 0;
    }

    // ---- phase A: attention weights (56 threads: h x 28 v) ----
    if (tid < 56) {
        const int h = tid / 28;
        const int v = tid % 28;
        const float* sf = s + h * NPOS + b * SP;
        float l[KT], msk[KT];
        #pragma unroll
        for (int k = 0; k < KT; ++k) {
            const int dt = k / 9 - 1, du = (k / 3) % 3 - 1, dv = k % 3 - 1;
            const int tt = t + dt, uu = u0 + du, vv = v + dv;
            const bool ok = (unsigned)tt < TT && (unsigned)uu < HH && (unsigned)vv < WW;
            l[k]   = ok ? sf[(tt * HH + uu) * WW + vv] : 0.f;  // pad logit = 0
            msk[k] = ok ? 1.f : 0.f;
        }
        float m = l[0];
        #pragma unroll
        for (int k = 1; k < KT; ++k) m = fmaxf(m, l[k]);
        float sum = 0.f;
        #pragma unroll
        for (int k = 0; k < KT; ++k) { l[k] = __expf(l[k] - m); sum += l[k]; }
        const float inv = 1.f / sum;
        const int half = v / 14, vi = v % 14;
        #pragma unroll
        for (int k = 0; k < KT; ++k)
            s_aw[k][h][half * 16 + vi] = l[k] * inv * msk[k];  // OOB weight = 0
    }
    __syncthreads();

    // ---- phase B: thread = (c, half); half is wave-uniform (tid>>7) ----
    {
        const int c = tid & 127;
        const int h = c & 1;
        const float* xc = x + (size_t)(b * CC + c) * SP;
        if (tid < 128) phaseB_row<0>(xc, s_aw, h, t, u0, s_mt, c);
        else           phaseB_row<1>(xc, s_aw, h, t, u0, s_mt, c);
    }
    __syncthreads();

    // ---- phase C: out = Wb @ merged via MFMA ----
    const int w    = tid >> 6;
    const int lane = tid & 63;
    const int lr   = lane & 15;
    const int lk   = lane >> 4;

    #pragma unroll
    for (int ci2 = 0; ci2 < 2; ++ci2) {
        const int cot = w * 2 + ci2;
        const int cob = cot * 16 + lk * 4;       // D row base for this lane
        f32x4 acc0, acc1;                        // pt = 0, 1
        #pragma unroll
        for (int r = 0; r < 4; ++r) { acc0[r] = bout[cob + r]; acc1[r] = acc0[r]; }

        #pragma unroll
        for (int ks = 0; ks < 4; ++ks) {
            const bf16x8 aA = *(const bf16x8*)&Wb[(size_t)(cot * 16 + lr) * CC + ks * 32 + lk * 8];
            const bf16x8 b0 = *(const bf16x8*)&s_mt[lr     ][ks * 32 + lk * 8];
            const bf16x8 b1 = *(const bf16x8*)&s_mt[16 + lr][ks * 32 + lk * 8];
            acc0 = __builtin_amdgcn_mfma_f32_16x16x32_bf16(aA, b0, acc0, 0, 0, 0);
            acc1 = __builtin_amdgcn_mfma_f32_16x16x32_bf16(aA, b1, acc1, 0, 0, 0);
        }
        const size_t ob = (size_t)b * CC * SP + p0;
        #pragma unroll
        for (int r = 0; r < 4; ++r)
            out[ob + (size_t)(cob + r) * SP + lr] = acc0[r];
        if (lr < 12) {                           // pos = 16+lr < 28
            #pragma unroll
            for (int r = 0; r < 4; ++r)
                out[ob + (size_t)(cob + r) * SP + 16 + lr] = acc1[r];
        }
    }
}

// ---------- cooperative mono kernel ----------

__global__ __launch_bounds__(256, 4) void mono_kernel(
    const float* __restrict__ x, const float* __restrict__ q,
    const float* __restrict__ Wout, const float* __restrict__ bout,
    float* __restrict__ out, float* __restrict__ s,
    unsigned short* __restrict__ Wb)
{
    __shared__ float4 sp[16][32];              // part-1 reduce buffer, 8 KB
    __shared__ float s_aw[KT][2][32];
    __shared__ unsigned short s_mt[32][MTS];

    const int bid = blockIdx.x;
    const int tid = threadIdx.x;

    // ---- part 1: s-field (blocks 0..195) + W->bf16 (blocks 196..259) ----
    if (bid < 196) {
        qfield_body(x, q, s, bid, tid, sp);
    } else if (bid < 196 + 64) {
        const int i = (bid - 196) * 256 + tid;   // 16384
        Wb[i] = bf16_rtne(Wout[i]);
    }
    __threadfence();
    cg::this_grid().sync();

    // ---- part 2: fusedmp over 896 tiles (8 XCD x 112, swizzled) ----
    const int pb = (bid & 7) * 112 + (bid >> 3);
    fusedmp_body(x, s, Wb, bout, out, pb, tid, s_aw, s_mt);
}

// ---------- fallback two-kernel path (r20, proven 43.9us) ----------

__global__ __launch_bounds__(256) void qfieldw_kernel(
    const float* __restrict__ x, const float* __restrict__ q,
    float* __restrict__ s,
    const float* __restrict__ Wout, unsigned short* __restrict__ Wb)
{
    __shared__ float4 sp[16][32];
    if (blockIdx.x >= 196) {
        const int i = (blockIdx.x - 196) * 256 + threadIdx.x;   // 16384
        Wb[i] = bf16_rtne(Wout[i]);
        return;
    }
    qfield_body(x, q, s, blockIdx.x, threadIdx.x, sp);
}

__global__ __launch_bounds__(256) void fusedmp_kernel(
    const float* __restrict__ x, const float* __restrict__ s,
    const unsigned short* __restrict__ Wb, const float* __restrict__ bout,
    float* __restrict__ out)
{
    __shared__ float s_aw[KT][2][32];
    __shared__ unsigned short s_mt[32][MTS];
    const int pb = (blockIdx.x & 7) * 112 + (blockIdx.x >> 3);
    fusedmp_body(x, s, Wb, bout, out, pb, threadIdx.x, s_aw, s_mt);
}

extern "C" void kernel_launch(void* const* d_in, const int* in_sizes, int n_in,
                              void* d_out, int out_size, void* d_ws, size_t ws_size,
                              hipStream_t stream) {
    const float* x    = (const float*)d_in[0];
    const float* q    = (const float*)d_in[1];
    const float* Wout = (const float*)d_in[2];
    const float* bout = (const float*)d_in[3];
    float* out = (float*)d_out;

    float* s = (float*)d_ws;                                  // 2*NPOS f32
    unsigned short* Wb = (unsigned short*)(s + 2 * NPOS);     // 16384 u16

    void* args[] = { (void*)&x, (void*)&q, (void*)&Wout, (void*)&bout,
                     (void*)&out, (void*)&s, (void*)&Wb };
    hipError_t err = hipLaunchCooperativeKernel(
        (const void*)mono_kernel, dim3(2 * 448), dim3(256), args, 0, stream);

    if (err != hipSuccess) {
        // deterministic fallback: proven r20 two-kernel pipeline
        qfieldw_kernel<<<dim3(196 + 64), dim3(256), 0, stream>>>(x, q, s, Wout, Wb);
        fusedmp_kernel<<<dim3(2 * 448),  dim3(256), 0, stream>>>(x, s, Wb, bout, out);
    }
}

// Round 22
// 43.942 us; speedup vs baseline: 5.0127x; 5.0127x over previous
//
#include <hip/hip_runtime.h>

// AttentiveConv3d: B=2, C=128, T=16, H=W=28, heads=2, HS=64, K=27 (3x3x3, pad 1)
// Round 22: revert to r20 (best measured: 43.9us, 11.2x over baseline).
// r21's cooperative mono-kernel (grid.sync) was a 5x regression — reverted.
//   K1 qfieldw: blocks 0..195 s-field (f4); blocks 196..259 W->bf16
//   K2 fusedmp: A) softmax -> s_aw; B) row-major merge (templated halves);
//               C) MFMA projection (+bias). XCD-swizzled grid 896 = 8x112.

#define TT 16
#define HH 28
#define WW 28
#define CC 128
#define SP (TT * HH * WW)   // 12544 = 448*28, 98*128
#define NPOS (2 * SP)       // 25088 = 196*128
#define HS 64
#define KT 27
#define MTS 136             // padded bf16 stride for s_mt

typedef __attribute__((ext_vector_type(8))) short bf16x8;
typedef __attribute__((ext_vector_type(4))) float f32x4;

#define CLMP(a) ((a) < 0 ? 0 : ((a) > 15 ? 15 : (a)))

__device__ __forceinline__ unsigned short bf16_rtne(float f) {
    unsigned u = __float_as_uint(f);
    unsigned r = (u + 0x7FFFu + ((u >> 16) & 1u)) >> 16;
    return (unsigned short)r;
}

// blocks 0..195: s-field over 128 consecutive positions (f4 per lane);
// blocks 196..259: Wout -> bf16.
__global__ __launch_bounds__(256) void qfieldw_kernel(
    const float* __restrict__ x, const float* __restrict__ q,
    float* __restrict__ s,
    const float* __restrict__ Wout, unsigned short* __restrict__ Wb)
{
    if (blockIdx.x >= 196) {
        const int i = (blockIdx.x - 196) * 256 + threadIdx.x;   // 16384
        Wb[i] = bf16_rtne(Wout[i]);
        return;
    }
    __shared__ float4 sp[16][32];     // [h*8+g][p4 slot], 8 KB
    const int tid = threadIdx.x;
    const int pl  = tid & 31;         // f4 slot within block
    const int g   = tid >> 5;         // channel group 0..7
    const int p   = blockIdx.x * 128 + pl * 4;   // 128 | SP -> same batch
    const int b   = p / SP;
    const int si  = p % SP;
    const float* xb = x + (size_t)b * CC * SP + si;

    float4 a0 = make_float4(0.f, 0.f, 0.f, 0.f);
    float4 a1 = make_float4(0.f, 0.f, 0.f, 0.f);
    #pragma unroll
    for (int j = 0; j < 16; ++j) {
        const int c = g * 16 + j;
        const float4 val = *(const float4*)&xb[(size_t)c * SP];
        const float qv   = q[(c & 1) * HS + (c >> 1)] * (1.0f / 64.0f);
        if (c & 1) {
            a1.x += qv * val.x; a1.y += qv * val.y;
            a1.z += qv * val.z; a1.w += qv * val.w;
        } else {
            a0.x += qv * val.x; a0.y += qv * val.y;
            a0.z += qv * val.z; a0.w += qv * val.w;
        }
    }
    sp[g][pl]     = a0;
    sp[8 + g][pl] = a1;
    __syncthreads();
    if (tid < 64) {
        const int h = tid >> 5, pp = tid & 31;
        float4 a = make_float4(0.f, 0.f, 0.f, 0.f);
        #pragma unroll
        for (int g2 = 0; g2 < 8; ++g2) {
            const float4 v = sp[h * 8 + g2][pp];
            a.x += v.x; a.y += v.y; a.z += v.z; a.w += v.w;
        }
        *(float4*)&s[h * NPOS + blockIdx.x * 128 + pp * 4] = a;
    }
}

// phase B worker: HALF is compile-time -> all xr/acc indices constant-fold.
template<int HALF>
__device__ __forceinline__ void phaseB_row(
    const float* __restrict__ xc, const float (*s_aw)[2][32], int h,
    int t, int u0, unsigned short (*s_mt)[MTS], int c)
{
    float acc[16];
    #pragma unroll
    for (int i = 0; i < 16; ++i) acc[i] = 0.f;

    #pragma unroll
    for (int dt = -1; dt <= 1; ++dt) {
        #pragma unroll
        for (int du = -1; du <= 1; ++du) {
            const int tt = t + dt, uu = u0 + du;
            const bool rok = ((unsigned)tt < TT) && ((unsigned)uu < HH);
            const int rbase = rok ? (tt * HH + uu) * WW : 0;  // aw=0 if row OOB
            float xr[16];                       // vv = HALF*12 .. HALF*12+15
            #pragma unroll
            for (int j = 0; j < 4; ++j) {
                const float4 tmp = *(const float4*)&xc[rbase + HALF * 12 + 4 * j];
                xr[4*j+0] = tmp.x; xr[4*j+1] = tmp.y;
                xr[4*j+2] = tmp.z; xr[4*j+3] = tmp.w;
            }
            const int kb = ((dt + 1) * 3 + (du + 1)) * 3;     // k = kb + dv
            #pragma unroll
            for (int dv = 0; dv < 3; ++dv) {
                const float4* aw4 = (const float4*)&s_aw[kb + dv][h][HALF * 16];
                #pragma unroll
                for (int j = 0; j < 4; ++j) {
                    const float4 a4 = aw4[j];
                    const int ib = 4 * j;
                    // xr index = i + (dv-1) + 2*HALF; clamped only where aw==0
                    acc[ib+0] += a4.x * xr[CLMP(ib+0 + dv - 1 + 2*HALF)];
                    acc[ib+1] += a4.y * xr[CLMP(ib+1 + dv - 1 + 2*HALF)];
                    acc[ib+2] += a4.z * xr[CLMP(ib+2 + dv - 1 + 2*HALF)];
                    acc[ib+3] += a4.w * xr[CLMP(ib+3 + dv - 1 + 2*HALF)];
                }
            }
        }
    }
    #pragma unroll
    for (int i = 0; i < 14; ++i)                 // i=14,15 are dummies
        s_mt[HALF * 14 + i][c] = bf16_rtne(acc[i]);
}

// block = 28-p tile = one (b,t,u0) row. grid 896 = 8 XCD x 112, swizzled.
__global__ __launch_bounds__(256) void fusedmp_kernel(
    const float* __restrict__ x, const float* __restrict__ s,
    const unsigned short* __restrict__ Wb, const float* __restrict__ bout,
    float* __restrict__ out)
{
    __shared__ float s_aw[KT][2][32];          // halves at [0..13] and [16..29]
    __shared__ unsigned short s_mt[32][MTS];   // rows 28..31 zero-padded

    const int pb   = (blockIdx.x & 7) * 112 + (blockIdx.x >> 3);
    const int b    = pb / 448;                 // 448 rows per batch
    const int tile = pb % 448;
    const int p0   = tile * 28;
    const int t    = tile / 28;                // 0..15
    const int u0   = tile % 28;                // 0..27
    const int tid  = threadIdx.x;

    // zero pad rows 28..31 of s_mt (phase C reads them in the tail p-tile)
    {
        unsigned* z = (unsigned*)&s_mt[28][0];    // 4*MTS u16 = 2*MTS words
        for (int i = tid; i < 2 * MTS; i += 256) z[i] = 0;
    }

    // ---- phase A: attention weights (56 threads: h x 28 v) ----
    if (tid < 56) {
        const int h = tid / 28;
        const int v = tid % 28;
        const float* sf = s + h * NPOS + b * SP;
        float l[KT], msk[KT];
        #pragma unroll
        for (int k = 0; k < KT; ++k) {
            const int dt = k / 9 - 1, du = (k / 3) % 3 - 1, dv = k % 3 - 1;
            const int tt = t + dt, uu = u0 + du, vv = v + dv;
            const bool ok = (unsigned)tt < TT && (unsigned)uu < HH && (unsigned)vv < WW;
            l[k]   = ok ? sf[(tt * HH + uu) * WW + vv] : 0.f;  // pad logit = 0
            msk[k] = ok ? 1.f : 0.f;
        }
        float m = l[0];
        #pragma unroll
        for (int k = 1; k < KT; ++k) m = fmaxf(m, l[k]);
        float sum = 0.f;
        #pragma unroll
        for (int k = 0; k < KT; ++k) { l[k] = __expf(l[k] - m); sum += l[k]; }
        const float inv = 1.f / sum;
        const int half = v / 14, vi = v % 14;
        #pragma unroll
        for (int k = 0; k < KT; ++k)
            s_aw[k][h][half * 16 + vi] = l[k] * inv * msk[k];  // OOB weight = 0
    }
    __syncthreads();

    // ---- phase B: thread = (c, half); half is wave-uniform (tid>>7) ----
    {
        const int c = tid & 127;
        const int h = c & 1;
        const float* xc = x + (size_t)(b * CC + c) * SP;
        if (tid < 128) phaseB_row<0>(xc, s_aw, h, t, u0, s_mt, c);
        else           phaseB_row<1>(xc, s_aw, h, t, u0, s_mt, c);
    }
    __syncthreads();

    // ---- phase C: out = Wb @ merged via MFMA (r17 package, 28-col tail) ----
    const int w    = tid >> 6;
    const int lane = tid & 63;
    const int lr   = lane & 15;
    const int lk   = lane >> 4;

    #pragma unroll
    for (int ci2 = 0; ci2 < 2; ++ci2) {
        const int cot = w * 2 + ci2;
        const int cob = cot * 16 + lk * 4;       // D row base for this lane
        f32x4 acc0, acc1;                        // pt = 0, 1
        #pragma unroll
        for (int r = 0; r < 4; ++r) { acc0[r] = bout[cob + r]; acc1[r] = acc0[r]; }

        #pragma unroll
        for (int ks = 0; ks < 4; ++ks) {
            const bf16x8 aA = *(const bf16x8*)&Wb[(size_t)(cot * 16 + lr) * CC + ks * 32 + lk * 8];
            const bf16x8 b0 = *(const bf16x8*)&s_mt[lr     ][ks * 32 + lk * 8];
            const bf16x8 b1 = *(const bf16x8*)&s_mt[16 + lr][ks * 32 + lk * 8];
            acc0 = __builtin_amdgcn_mfma_f32_16x16x32_bf16(aA, b0, acc0, 0, 0, 0);
            acc1 = __builtin_amdgcn_mfma_f32_16x16x32_bf16(aA, b1, acc1, 0, 0, 0);
        }
        const size_t ob = (size_t)b * CC * SP + p0;
        #pragma unroll
        for (int r = 0; r < 4; ++r)
            out[ob + (size_t)(cob + r) * SP + lr] = acc0[r];
        if (lr < 12) {                           // pos = 16+lr < 28
            #pragma unroll
            for (int r = 0; r < 4; ++r)
                out[ob + (size_t)(cob + r) * SP + 16 + lr] = acc1[r];
        }
    }
}

extern "C" void kernel_launch(void* const* d_in, const int* in_sizes, int n_in,
                              void* d_out, int out_size, void* d_ws, size_t ws_size,
                              hipStream_t stream) {
    const float* x    = (const float*)d_in[0];
    const float* q    = (const float*)d_in[1];
    const float* Wout = (const float*)d_in[2];
    const float* bout = (const float*)d_in[3];
    float* out = (float*)d_out;

    float* s = (float*)d_ws;                                  // 2*NPOS f32
    unsigned short* Wb = (unsigned short*)(s + 2 * NPOS);     // 16384 u16

    qfieldw_kernel<<<dim3(196 + 64), dim3(256), 0, stream>>>(x, q, s, Wout, Wb);
    fusedmp_kernel<<<dim3(2 * 448),  dim3(256), 0, stream>>>(x, s, Wb, bout, out);
}

// Round 23
// 43.460 us; speedup vs baseline: 5.0683x; 1.0111x over previous
//
#include <hip/hip_runtime.h>

// AttentiveConv3d: B=2, C=128, T=16, H=W=28, heads=2, HS=64, K=27 (3x3x3, pad 1)
// Round 23: r22 fusedmp byte-identical; qfieldw re-chunked to 448 blocks of
// 56 positions with the SAME bijective XCD swizzle as fusedmp — each XCD's
// L2 is pre-warmed with exactly the x slab its fusedmp blocks will read
// (~3.2 MB < 4 MB L2). Mechanism: fusedmp is latency-bound on cold-x loads;
// warm L2 cuts ~900cy HBM latency to ~200cy.
//   K1 qfieldw: blocks 0..447 s-field (56-p chunks, swizzled); 448..511 W->bf16
//   K2 fusedmp: A) softmax -> s_aw; B) row-major merge; C) MFMA proj (+bias)

#define TT 16
#define HH 28
#define WW 28
#define CC 128
#define SP (TT * HH * WW)   // 12544 = 448*28 = 224*56
#define NPOS (2 * SP)       // 25088
#define HS 64
#define KT 27
#define MTS 136             // padded bf16 stride for s_mt

typedef __attribute__((ext_vector_type(8))) short bf16x8;
typedef __attribute__((ext_vector_type(4))) float f32x4;

#define CLMP(a) ((a) < 0 ? 0 : ((a) > 15 ? 15 : (a)))

__device__ __forceinline__ unsigned short bf16_rtne(float f) {
    unsigned u = __float_as_uint(f);
    unsigned r = (u + 0x7FFFu + ((u >> 16) & 1u)) >> 16;
    return (unsigned short)r;
}

// blocks 0..447: s-field over 56-position chunks, XCD-swizzled to match
// fusedmp's slab ownership; blocks 448..511: Wout -> bf16.
__global__ __launch_bounds__(256) void qfieldw_kernel(
    const float* __restrict__ x, const float* __restrict__ q,
    float* __restrict__ s,
    const float* __restrict__ Wout, unsigned short* __restrict__ Wb)
{
    if (blockIdx.x >= 448) {
        const int i = (blockIdx.x - 448) * 256 + threadIdx.x;   // 16384
        Wb[i] = bf16_rtne(Wout[i]);
        return;
    }
    // swizzle matches fusedmp: XCD j owns chunks [j*56, (j+1)*56)
    // = positions [j*3136, (j+1)*3136) — the same slab its fusedmp tiles read.
    const int cq  = (blockIdx.x & 7) * 56 + (blockIdx.x >> 3);  // 448 = 8*56
    __shared__ float4 sp[32][14];     // [h*16+g][f4 slot], 7 KB
    const int tid = threadIdx.x;

    if (tid < 224) {
        const int g  = tid / 14;      // channel group 0..15 (8 channels each)
        const int pl = tid % 14;      // f4 slot within chunk
        const int p  = cq * 56 + pl * 4;   // 56 | SP -> same batch
        const int b  = p / SP;
        const int si = p % SP;
        const float* xb = x + (size_t)b * CC * SP + si;

        float4 a0 = make_float4(0.f, 0.f, 0.f, 0.f);
        float4 a1 = make_float4(0.f, 0.f, 0.f, 0.f);
        #pragma unroll
        for (int j = 0; j < 8; ++j) {
            const int c = g * 8 + j;
            const float4 val = *(const float4*)&xb[(size_t)c * SP];
            const float qv   = q[(c & 1) * HS + (c >> 1)] * (1.0f / 64.0f);
            if (c & 1) {
                a1.x += qv * val.x; a1.y += qv * val.y;
                a1.z += qv * val.z; a1.w += qv * val.w;
            } else {
                a0.x += qv * val.x; a0.y += qv * val.y;
                a0.z += qv * val.z; a0.w += qv * val.w;
            }
        }
        sp[g][pl]      = a0;
        sp[16 + g][pl] = a1;
    }
    __syncthreads();
    if (tid < 28) {
        const int h = tid / 14, pp = tid % 14;
        float4 a = make_float4(0.f, 0.f, 0.f, 0.f);
        #pragma unroll
        for (int g2 = 0; g2 < 16; ++g2) {
            const float4 v = sp[h * 16 + g2][pp];
            a.x += v.x; a.y += v.y; a.z += v.z; a.w += v.w;
        }
        *(float4*)&s[h * NPOS + cq * 56 + pp * 4] = a;
    }
}

// phase B worker: HALF is compile-time -> all xr/acc indices constant-fold.
template<int HALF>
__device__ __forceinline__ void phaseB_row(
    const float* __restrict__ xc, const float (*s_aw)[2][32], int h,
    int t, int u0, unsigned short (*s_mt)[MTS], int c)
{
    float acc[16];
    #pragma unroll
    for (int i = 0; i < 16; ++i) acc[i] = 0.f;

    #pragma unroll
    for (int dt = -1; dt <= 1; ++dt) {
        #pragma unroll
        for (int du = -1; du <= 1; ++du) {
            const int tt = t + dt, uu = u0 + du;
            const bool rok = ((unsigned)tt < TT) && ((unsigned)uu < HH);
            const int rbase = rok ? (tt * HH + uu) * WW : 0;  // aw=0 if row OOB
            float xr[16];                       // vv = HALF*12 .. HALF*12+15
            #pragma unroll
            for (int j = 0; j < 4; ++j) {
                const float4 tmp = *(const float4*)&xc[rbase + HALF * 12 + 4 * j];
                xr[4*j+0] = tmp.x; xr[4*j+1] = tmp.y;
                xr[4*j+2] = tmp.z; xr[4*j+3] = tmp.w;
            }
            const int kb = ((dt + 1) * 3 + (du + 1)) * 3;     // k = kb + dv
            #pragma unroll
            for (int dv = 0; dv < 3; ++dv) {
                const float4* aw4 = (const float4*)&s_aw[kb + dv][h][HALF * 16];
                #pragma unroll
                for (int j = 0; j < 4; ++j) {
                    const float4 a4 = aw4[j];
                    const int ib = 4 * j;
                    // xr index = i + (dv-1) + 2*HALF; clamped only where aw==0
                    acc[ib+0] += a4.x * xr[CLMP(ib+0 + dv - 1 + 2*HALF)];
                    acc[ib+1] += a4.y * xr[CLMP(ib+1 + dv - 1 + 2*HALF)];
                    acc[ib+2] += a4.z * xr[CLMP(ib+2 + dv - 1 + 2*HALF)];
                    acc[ib+3] += a4.w * xr[CLMP(ib+3 + dv - 1 + 2*HALF)];
                }
            }
        }
    }
    #pragma unroll
    for (int i = 0; i < 14; ++i)                 // i=14,15 are dummies
        s_mt[HALF * 14 + i][c] = bf16_rtne(acc[i]);
}

// block = 28-p tile = one (b,t,u0) row. grid 896 = 8 XCD x 112, swizzled.
__global__ __launch_bounds__(256) void fusedmp_kernel(
    const float* __restrict__ x, const float* __restrict__ s,
    const unsigned short* __restrict__ Wb, const float* __restrict__ bout,
    float* __restrict__ out)
{
    __shared__ float s_aw[KT][2][32];          // halves at [0..13] and [16..29]
    __shared__ unsigned short s_mt[32][MTS];   // rows 28..31 zero-padded

    const int pb   = (blockIdx.x & 7) * 112 + (blockIdx.x >> 3);
    const int b    = pb / 448;                 // 448 rows per batch
    const int tile = pb % 448;
    const int p0   = tile * 28;
    const int t    = tile / 28;                // 0..15
    const int u0   = tile % 28;                // 0..27
    const int tid  = threadIdx.x;

    // zero pad rows 28..31 of s_mt (phase C reads them in the tail p-tile)
    {
        unsigned* z = (unsigned*)&s_mt[28][0];    // 4*MTS u16 = 2*MTS words
        for (int i = tid; i < 2 * MTS; i += 256) z[i] = 0;
    }

    // ---- phase A: attention weights (56 threads: h x 28 v) ----
    if (tid < 56) {
        const int h = tid / 28;
        const int v = tid % 28;
        const float* sf = s + h * NPOS + b * SP;
        float l[KT], msk[KT];
        #pragma unroll
        for (int k = 0; k < KT; ++k) {
            const int dt = k / 9 - 1, du = (k / 3) % 3 - 1, dv = k % 3 - 1;
            const int tt = t + dt, uu = u0 + du, vv = v + dv;
            const bool ok = (unsigned)tt < TT && (unsigned)uu < HH && (unsigned)vv < WW;
            l[k]   = ok ? sf[(tt * HH + uu) * WW + vv] : 0.f;  // pad logit = 0
            msk[k] = ok ? 1.f : 0.f;
        }
        float m = l[0];
        #pragma unroll
        for (int k = 1; k < KT; ++k) m = fmaxf(m, l[k]);
        float sum = 0.f;
        #pragma unroll
        for (int k = 0; k < KT; ++k) { l[k] = __expf(l[k] - m); sum += l[k]; }
        const float inv = 1.f / sum;
        const int half = v / 14, vi = v % 14;
        #pragma unroll
        for (int k = 0; k < KT; ++k)
            s_aw[k][h][half * 16 + vi] = l[k] * inv * msk[k];  // OOB weight = 0
    }
    __syncthreads();

    // ---- phase B: thread = (c, half); half is wave-uniform (tid>>7) ----
    {
        const int c = tid & 127;
        const int h = c & 1;
        const float* xc = x + (size_t)(b * CC + c) * SP;
        if (tid < 128) phaseB_row<0>(xc, s_aw, h, t, u0, s_mt, c);
        else           phaseB_row<1>(xc, s_aw, h, t, u0, s_mt, c);
    }
    __syncthreads();

    // ---- phase C: out = Wb @ merged via MFMA (r17 package, 28-col tail) ----
    const int w    = tid >> 6;
    const int lane = tid & 63;
    const int lr   = lane & 15;
    const int lk   = lane >> 4;

    #pragma unroll
    for (int ci2 = 0; ci2 < 2; ++ci2) {
        const int cot = w * 2 + ci2;
        const int cob = cot * 16 + lk * 4;       // D row base for this lane
        f32x4 acc0, acc1;                        // pt = 0, 1
        #pragma unroll
        for (int r = 0; r < 4; ++r) { acc0[r] = bout[cob + r]; acc1[r] = acc0[r]; }

        #pragma unroll
        for (int ks = 0; ks < 4; ++ks) {
            const bf16x8 aA = *(const bf16x8*)&Wb[(size_t)(cot * 16 + lr) * CC + ks * 32 + lk * 8];
            const bf16x8 b0 = *(const bf16x8*)&s_mt[lr     ][ks * 32 + lk * 8];
            const bf16x8 b1 = *(const bf16x8*)&s_mt[16 + lr][ks * 32 + lk * 8];
            acc0 = __builtin_amdgcn_mfma_f32_16x16x32_bf16(aA, b0, acc0, 0, 0, 0);
            acc1 = __builtin_amdgcn_mfma_f32_16x16x32_bf16(aA, b1, acc1, 0, 0, 0);
        }
        const size_t ob = (size_t)b * CC * SP + p0;
        #pragma unroll
        for (int r = 0; r < 4; ++r)
            out[ob + (size_t)(cob + r) * SP + lr] = acc0[r];
        if (lr < 12) {                           // pos = 16+lr < 28
            #pragma unroll
            for (int r = 0; r < 4; ++r)
                out[ob + (size_t)(cob + r) * SP + 16 + lr] = acc1[r];
        }
    }
}

extern "C" void kernel_launch(void* const* d_in, const int* in_sizes, int n_in,
                              void* d_out, int out_size, void* d_ws, size_t ws_size,
                              hipStream_t stream) {
    const float* x    = (const float*)d_in[0];
    const float* q    = (const float*)d_in[1];
    const float* Wout = (const float*)d_in[2];
    const float* bout = (const float*)d_in[3];
    float* out = (float*)d_out;

    float* s = (float*)d_ws;                                  // 2*NPOS f32
    unsigned short* Wb = (unsigned short*)(s + 2 * NPOS);     // 16384 u16

    qfieldw_kernel<<<dim3(448 + 64), dim3(256), 0, stream>>>(x, q, s, Wout, Wb);
    fusedmp_kernel<<<dim3(2 * 448),  dim3(256), 0, stream>>>(x, s, Wb, bout, out);
}